// Round 7
// baseline (247.811 us; speedup 1.0000x reference)
//
#include <hip/hip_runtime.h>

// TorchGrouper: G=40000, O=64 offsets (4^3 hollow cube), C=64 channels.
// vox: int32 [2,40,400,400]; gpos: f32 [G,4] (b,z,y,x); feat: f32 [100000,64].
// Out concat: sampled_features [1,64,G,64] | gpf [1,3,G,64] | empty_mask [G]
// R6->R7 (Model D test): block = 16 waves = 16 g. 4 channel-chunks of 16.
// Stage [16c][16g][64o] in 64KB LDS, drain wave-per-plane as 4KB contiguous
// runs. Fewer planes in flight (16 vs 67), 4x longer runs, adjacent blocks
// write adjacent segments. Reads touch each feature cache line exactly once.

typedef float f32x4 __attribute__((ext_vector_type(4)));

constexpr int G  = 40000;
constexpr int C  = 64;
constexpr int VZ = 40, VY = 400, VX = 400;
constexpr size_t GO = (size_t)G * 64;
constexpr int GB   = 16;              // g's per block
constexpr int NBLK = G / GB;          // 2500

__device__ __forceinline__ void store_sysnt_x4(float* p, f32x4 v) {
    asm volatile("global_store_dwordx4 %0, %1, off sc0 sc1 nt"
                 :: "v"(p), "v"(v) : "memory");
}
__device__ __forceinline__ void store_sysnt_x1(float* p, float v) {
    asm volatile("global_store_dword %0, %1, off sc0 sc1 nt"
                 :: "v"(p), "v"(v) : "memory");
}

__global__ __launch_bounds__(1024, 8) void grouper_kernel(
    const int*   __restrict__ vox,
    const float* __restrict__ gpos,
    const float* __restrict__ feat,
    float*       __restrict__ out)
{
    __shared__ __align__(16) float sf[16 * 1024];   // 64 KB: [c16][g16][o64]

    const int wave = threadIdx.x >> 6;    // 0..15 == local g
    const int lane = threadIdx.x & 63;    // == o
    const int g = blockIdx.x * GB + wave;
    const int o = lane;

    // offsets r = {-3,-2,1,2}
    const int rtab4[4] = {-3, -2, 1, 2};
    const int rx = rtab4[o & 3];          // added to z
    const int ry = rtab4[(o >> 2) & 3];   // added to y
    const int rz = rtab4[(o >> 4) & 3];   // added to x

    const float4 p = ((const float4*)gpos)[g];        // (b,z,y,x)
    const float zf = p.y + (float)rx;
    const float yf = p.z + (float)ry;
    const float xf = p.w + (float)rz;

    const int bi = (int)p.x;                          // trunc-toward-zero
    const int zi = min(max((int)zf, 0), VZ - 1);
    const int yi = min(max((int)yf, 0), VY - 1);
    const int xi = min(max((int)xf, 0), VX - 1);

    const int idx = vox[((bi * VZ + zi) * VY + yi) * VX + xi];

    // ---- gpf [1,3,G,64] + empty mask (sys-nt, proven +3% in R6)
    float* gout = out + C * GO;
    const size_t t = (size_t)g * 64 + o;
    store_sysnt_x1(gout + t,          zf - truncf(zf));
    store_sysnt_x1(gout + GO + t,     yf - truncf(yf) + (float)rx);
    store_sysnt_x1(gout + 2 * GO + t, xf - truncf(xf) + (float)ry);
    const int allm1 = __all(idx == -1);
    if (o == 0) store_sysnt_x1(gout + 3 * GO + g, allm1 ? 1.0f : 0.0f);

    // ---- sampled_features: 4 chunks of 16 channels
    const bool  emp = idx < 0;
    const float* src = feat + (size_t)(emp ? 0 : idx) * C;
    const int   base = wave * 64 + lane;              // [g][o] within a plane

    #pragma unroll 1
    for (int cc = 0; cc < 4; ++cc) {
        // stage-load: 64B of the feature row (one cache line, touched once)
        f32x4 v0 = *(const f32x4*)(src + cc * 16 + 0);
        f32x4 v1 = *(const f32x4*)(src + cc * 16 + 4);
        f32x4 v2 = *(const f32x4*)(src + cc * 16 + 8);
        f32x4 v3 = *(const f32x4*)(src + cc * 16 + 12);
        if (emp) {
            v0 = (f32x4)0.0f; v1 = (f32x4)0.0f; v2 = (f32x4)0.0f; v3 = (f32x4)0.0f;
        }
        __syncthreads();                 // previous drain done; sf reusable
        sf[base +  0 * 1024] = v0.x; sf[base +  1 * 1024] = v0.y;
        sf[base +  2 * 1024] = v0.z; sf[base +  3 * 1024] = v0.w;
        sf[base +  4 * 1024] = v1.x; sf[base +  5 * 1024] = v1.y;
        sf[base +  6 * 1024] = v1.z; sf[base +  7 * 1024] = v1.w;
        sf[base +  8 * 1024] = v2.x; sf[base +  9 * 1024] = v2.y;
        sf[base + 10 * 1024] = v2.z; sf[base + 11 * 1024] = v2.w;
        sf[base + 12 * 1024] = v3.x; sf[base + 13 * 1024] = v3.y;
        sf[base + 14 * 1024] = v3.z; sf[base + 15 * 1024] = v3.w;
        __syncthreads();                 // stage complete

        // drain: wave w owns plane c = cc*16 + w; 4KB contiguous per block
        const float* lsrc = sf + wave * 1024;
        float* dst = out + (size_t)(cc * 16 + wave) * GO + (size_t)blockIdx.x * 1024;
        #pragma unroll
        for (int j = 0; j < 4; ++j) {
            f32x4 sv = *(const f32x4*)(lsrc + j * 256 + lane * 4);
            store_sysnt_x4(dst + j * 256 + lane * 4, sv);
        }
    }
}

extern "C" void kernel_launch(void* const* d_in, const int* in_sizes, int n_in,
                              void* d_out, int out_size, void* d_ws, size_t ws_size,
                              hipStream_t stream) {
    const int*   vox  = (const int*)d_in[0];
    const float* gpos = (const float*)d_in[1];
    const float* feat = (const float*)d_in[2];
    float*       out  = (float*)d_out;

    grouper_kernel<<<NBLK, 1024, 0, stream>>>(vox, gpos, feat, out);
}